// Round 16
// baseline (67.094 us; speedup 1.0000x reference)
//
#include <hip/hip_runtime.h>

#define SIZE 128
#define ROWS 32     // rows per tile
#define TPB 8       // tiles per block: 262144/32/8 = 1024 blocks = 4/CU
#define PITCH 136   // LDS row pitch in bf16; 272 B rows break pow2 bank stride

typedef short short8 __attribute__((ext_vector_type(8)));
typedef float f32x4 __attribute__((ext_vector_type(4)));

__device__ __forceinline__ unsigned short f2bf(float f) {
    unsigned int u = __float_as_uint(f);
    unsigned int r = u + 0x7FFFu + ((u >> 16) & 1u);
    return (unsigned short)(r >> 16);
}
__device__ __forceinline__ float bf2f(unsigned short h) {
    return __uint_as_float(((unsigned int)h) << 16);
}

// gr = Re(ifft(b)). DyT affine folded into the conv matrix:
//   Gt[c][k] = w[k] * gr[(c-k)&127]   (bf16, 32 KB)
//   C0[c]    = sum_k bias[k] * gr[(c-k)&127]   (f32, 512 B)
__global__ void build_gt(const float* __restrict__ br, const float* __restrict__ bi,
                         const float* __restrict__ w, const float* __restrict__ bias,
                         unsigned short* __restrict__ Gt, float* __restrict__ C0) {
    __shared__ float gr[SIZE];
    const int t = threadIdx.x;  // 0..127
    float acc = 0.0f;
    for (int j = 0; j < SIZE; ++j) {
        int p = (j * t) & 127;
        float a = (float)p * (1.0f / 64.0f);   // angle in units of pi
        acc += br[j] * cospif(a) - bi[j] * sinpif(a);
    }
    gr[t] = acc * (1.0f / 128.0f);
    __syncthreads();
    float c0 = 0.0f;
    for (int k = 0; k < SIZE; ++k) {
        const float g = gr[(t - k) & 127];
        c0 += bias[k] * g;
        Gt[t * SIZE + k] = f2bf(w[k] * g);
    }
    C0[t] = c0;
}

// out[r][c] = sum_k tanh(alpha*x[r][k]) * Gt[c][k] + C0[c] + x[r][c]
// R15's proven core (linear 1KB global I/O, LDS bounce both ways, NT
// stores preserving x in L3) made 8-tile PIPELINED per block:
//   stage(t+1) issue -> MFMA(t) -> B1 -> epi(t) [oA read + residual + NT
//   store] -> hwrite(t+1) [vmcnt wait LATE, ~1k cyc after issue] -> B2.
// Double-buffered hA/oA (34.8 KB -> 4 blocks/CU); vmcnt never drained.
__global__ __launch_bounds__(256, 4) void fourier_main(
    const float* __restrict__ x, const float* __restrict__ alpha_p,
    const unsigned short* __restrict__ Gt, const float* __restrict__ C0,
    float* __restrict__ out) {
    __shared__ unsigned short hA[2][ROWS * PITCH];  // bf16 tanh tiles
    __shared__ unsigned short oA[2][ROWS * PITCH];  // bf16 conv+C0 tiles

    const int tid = threadIdx.x;
    const int lane = tid & 63;
    const int wv = tid >> 6;
    const int lrow = lane & 15;   // fragment row selector
    const int slot = lane >> 4;   // fragment k-chunk / col-group selector
    const int colb = wv * 32;     // this wave's output column band

    // tanh(t) = 1 - 2/(1+2^(t*2*log2e))
    const float a2l = 2.0f * 1.44269504f * alpha_p[0];

    // ---- G fragments (8 KB/wave, L2-resident) + C0 for this wave's cols ----
    short8 gf[2][4];
    float4 c0v[2];
#pragma unroll
    for (int nt = 0; nt < 2; ++nt) {
        const int c = colb + nt * 16 + lrow;
#pragma unroll
        for (int kt = 0; kt < 4; ++kt)
            gf[nt][kt] = *reinterpret_cast<const short8*>(
                &Gt[c * SIZE + kt * 32 + slot * 8]);
        c0v[nt] = *reinterpret_cast<const float4*>(&C0[colb + nt * 16 + slot * 4]);
    }

    const unsigned blockBase = (unsigned)blockIdx.x * (TPB * ROWS * SIZE);
    const int srow = tid >> 5;        // linear map: row = i*8 + srow
    const int scol = (tid & 31) * 4;  //             col = scol

    // contiguous linear loads of tile t (issue-only; no wait here)
    auto stage = [&](int t, float4 (&xn)[4]) __attribute__((always_inline)) {
        const float* src = x + blockBase + (unsigned)t * (ROWS * SIZE);
#pragma unroll
        for (int i = 0; i < 4; ++i)
            xn[i] = *reinterpret_cast<const float4*>(&src[i * 1024 + tid * 4]);
    };
    // tanh once, linear order -> bf16 -> hA[buf] (first use of xn: vmcnt wait)
    auto hwrite = [&](int buf, const float4 (&xn)[4]) __attribute__((always_inline)) {
#pragma unroll
        for (int i = 0; i < 4; ++i) {
            ushort4 hq;
            float e;
            e = __builtin_amdgcn_exp2f(a2l * xn[i].x);
            hq.x = f2bf(fmaf(-2.0f, __builtin_amdgcn_rcpf(1.0f + e), 1.0f));
            e = __builtin_amdgcn_exp2f(a2l * xn[i].y);
            hq.y = f2bf(fmaf(-2.0f, __builtin_amdgcn_rcpf(1.0f + e), 1.0f));
            e = __builtin_amdgcn_exp2f(a2l * xn[i].z);
            hq.z = f2bf(fmaf(-2.0f, __builtin_amdgcn_rcpf(1.0f + e), 1.0f));
            e = __builtin_amdgcn_exp2f(a2l * xn[i].w);
            hq.w = f2bf(fmaf(-2.0f, __builtin_amdgcn_rcpf(1.0f + e), 1.0f));
            *reinterpret_cast<ushort4*>(&hA[buf][(i * 8 + srow) * PITCH + scol]) =
                hq;
        }
    };
    // MFMA on hA[pb] -> oA[pb] (fragment order, +C0)
    auto mfma_pass = [&](int pb) __attribute__((always_inline)) {
#pragma unroll
        for (int mt = 0; mt < 2; ++mt) {
            const int r = mt * 16 + lrow;
            short8 hf[4];
#pragma unroll
            for (int kt = 0; kt < 4; ++kt)
                hf[kt] = *reinterpret_cast<const short8*>(
                    &hA[pb][r * PITCH + kt * 32 + slot * 8]);
#pragma unroll
            for (int nt = 0; nt < 2; ++nt) {
                f32x4 a = {0.f, 0.f, 0.f, 0.f};
#pragma unroll
                for (int kt = 0; kt < 4; ++kt)
                    a = __builtin_amdgcn_mfma_f32_16x16x32_bf16(gf[nt][kt], hf[kt],
                                                                a, 0, 0, 0);
                ushort4 o;
                o.x = f2bf(a[0] + c0v[nt].x);
                o.y = f2bf(a[1] + c0v[nt].y);
                o.z = f2bf(a[2] + c0v[nt].z);
                o.w = f2bf(a[3] + c0v[nt].w);
                *reinterpret_cast<ushort4*>(
                    &oA[pb][r * PITCH + colb + nt * 16 + slot * 4]) = o;
            }
        }
    };
    // linear oA read + residual from regs + NONTEMPORAL contiguous store
    auto epi = [&](int t, int pb, const float4 (&xc)[4])
        __attribute__((always_inline)) {
        const unsigned tb = blockBase + (unsigned)t * (ROWS * SIZE);
#pragma unroll
        for (int i = 0; i < 4; ++i) {
            const ushort4 ov = *reinterpret_cast<const ushort4*>(
                &oA[pb][(i * 8 + srow) * PITCH + scol]);
            f32x4 r;
            r[0] = bf2f(ov.x) + xc[i].x;
            r[1] = bf2f(ov.y) + xc[i].y;
            r[2] = bf2f(ov.z) + xc[i].z;
            r[3] = bf2f(ov.w) + xc[i].w;
            __builtin_nontemporal_store(
                r, reinterpret_cast<f32x4*>(&out[tb + i * 1024 + tid * 4]));
        }
    };

    float4 xA[4], xB[4];  // rotating register sets: tile t and t+1

    // ---- prologue: tile 0 staged into hA[0] ----
    stage(0, xA);
    hwrite(0, xA);
    asm volatile("s_waitcnt lgkmcnt(0)\n\ts_barrier" ::: "memory");

    // ---- pipelined tile loop (unrolled x2 for static xA/xB rotation) ----
    auto tile_body = [&](int t, const float4 (&xc)[4], float4 (&xn)[4], int pb)
        __attribute__((always_inline)) {
        if (t + 1 < TPB) stage(t + 1, xn);  // issue early
        mfma_pass(pb);
        // B1: publish oA[pb]; hA[pb] reads retired
        asm volatile("s_waitcnt lgkmcnt(0)\n\ts_barrier" ::: "memory");
        epi(t, pb, xc);                      // no xn dependency -> wait stays late
        if (t + 1 < TPB) hwrite(pb ^ 1, xn); // vmcnt wait ~mfma+B1+epi after issue
        // B2: publish hA[pb^1]; oA[pb] reads retired before t+2 overwrites
        asm volatile("s_waitcnt lgkmcnt(0)\n\ts_barrier" ::: "memory");
    };

#pragma unroll
    for (int t = 0; t < TPB; t += 2) {
        tile_body(t, xA, xB, 0);
        tile_body(t + 1, xB, xA, 1);
    }
}

extern "C" void kernel_launch(void* const* d_in, const int* in_sizes, int n_in,
                              void* d_out, int out_size, void* d_ws, size_t ws_size,
                              hipStream_t stream) {
    const float* x = (const float*)d_in[0];
    const float* alpha = (const float*)d_in[1];
    const float* dyt_w = (const float*)d_in[2];
    const float* dyt_b = (const float*)d_in[3];
    // d_in[4] = a_real, d_in[5] = a_imag, d_in[8] = ffn_bias: dead code in reference
    const float* b_real = (const float*)d_in[6];
    const float* b_imag = (const float*)d_in[7];
    float* out = (float*)d_out;

    unsigned short* Gt = (unsigned short*)d_ws;            // 32 KB bf16
    float* C0 = (float*)((char*)d_ws + SIZE * SIZE * 2);   // 512 B f32

    build_gt<<<1, 128, 0, stream>>>(b_real, b_imag, dyt_w, dyt_b, Gt, C0);

    const int rows = out_size / SIZE;          // 262144
    const int nblocks = rows / (ROWS * TPB);   // 1024
    fourier_main<<<nblocks, 256, 0, stream>>>(x, alpha, Gt, C0, out);
}

// Round 17
// 64.433 us; speedup vs baseline: 1.0413x; 1.0413x over previous
//
#include <hip/hip_runtime.h>

#define SIZE 128
#define PADW 136   // LDS row pitch in bf16 elements; breaks pow2 stride

typedef short short8 __attribute__((ext_vector_type(8)));
typedef float f32x4 __attribute__((ext_vector_type(4)));

__device__ __forceinline__ unsigned short f2bf(float f) {
    unsigned int u = __float_as_uint(f);
    unsigned int r = u + 0x7FFFu + ((u >> 16) & 1u);
    return (unsigned short)(r >> 16);
}

// pack two f32 -> one u32 of 2 bf16 (RNE) in a single HW instruction
__device__ __forceinline__ unsigned int cvt_pk_bf16(float lo, float hi) {
    unsigned int r;
    asm("v_cvt_pk_bf16_f32 %0, %1, %2" : "=v"(r) : "v"(lo), "v"(hi));
    return r;
}

// gr = Re(ifft(b)). Folds DyT affine params into the conv matrix:
//   Gt[c][k] = w[k] * gr[(c-k)&127]   (bf16, 32 KB)
//   C0[c]    = sum_k bias[k] * gr[(c-k)&127]   (f32, 512 B at offset 32768)
__global__ void build_gt(const float* __restrict__ br, const float* __restrict__ bi,
                         const float* __restrict__ w, const float* __restrict__ bias,
                         unsigned short* __restrict__ Gt, float* __restrict__ C0) {
    __shared__ float gr[SIZE];
    const int t = threadIdx.x;  // 0..127
    float acc = 0.0f;
    for (int j = 0; j < SIZE; ++j) {
        int p = (j * t) & 127;                 // exact periodic reduction
        float a = (float)p * (1.0f / 64.0f);   // angle in units of pi
        acc += br[j] * cospif(a) - bi[j] * sinpif(a);
    }
    gr[t] = acc * (1.0f / 128.0f);
    __syncthreads();
    float c0 = 0.0f;
    for (int k = 0; k < SIZE; ++k) {
        const float g = gr[(t - k) & 127];
        c0 += bias[k] * g;
        Gt[t * SIZE + k] = f2bf(w[k] * g);
    }
    C0[t] = c0;
}

// out[r][c] = sum_k tanh(alpha*x[r][k]) * Gt[c][k] + C0[c] + x[r][c]
// R15 structure UNCHANGED (single 64-row tile/block, linear 1KB global I/O,
// LDS bounce hA in / halved oA out, NONTEMPORAL stores -> x stays L3-hot).
// VALU chain trimmed: 2*alpha*log2e folded into one constant (kills the
// hidden x*log2e mul inside __expf), and all f32->bf16 conversions use HW
// v_cvt_pk_bf16_f32 (1 instr / 2 elems) instead of 4-op manual RNE.
__global__ __launch_bounds__(256, 4) void fourier_main(
    const float* __restrict__ x, const float* __restrict__ alpha_p,
    const unsigned short* __restrict__ Gt, const float* __restrict__ C0,
    float* __restrict__ out) {
    __shared__ unsigned short hA[64 * PADW];  // bf16 tanh(alpha*x), full tile
    __shared__ unsigned short oA[32 * PADW];  // bf16 conv+C0, half tile bounce

    const int tid = threadIdx.x;
    const int lane = tid & 63;
    const int wid = tid >> 6;
    const int lrow = lane & 15;   // fragment row selector
    const int slot = lane >> 4;   // fragment k-chunk / col-group selector
    const int colb = wid * 32;

    // tanh(t) = 1 - 2/(1 + 2^(t*2*log2e))
    const float a2l = 2.0f * 1.44269504f * alpha_p[0];
    const unsigned base = (unsigned)blockIdx.x * (64u * SIZE);  // max 33.5M < 2^31

    // linear map: thread tid, pass j <-> tile row j*8 + rl, cols cl..cl+3
    const int rl = tid >> 5;        // 0..7
    const int cl = (tid & 31) * 4;  // 0..124

    // ---- 1. contiguous x loads (kept in regs for the residual) ----
    float4 xr[8];
#pragma unroll
    for (int j = 0; j < 8; ++j)
        xr[j] = *reinterpret_cast<const float4*>(&x[base + j * 1024 + tid * 4]);

    // ---- 2. h = tanh(alpha*x) -> bf16 (HW pack) -> hA ----
#pragma unroll
    for (int j = 0; j < 8; ++j) {
        float t0, t1, t2, t3, e;
        e = __builtin_amdgcn_exp2f(a2l * xr[j].x);
        t0 = fmaf(-2.0f, __builtin_amdgcn_rcpf(1.0f + e), 1.0f);
        e = __builtin_amdgcn_exp2f(a2l * xr[j].y);
        t1 = fmaf(-2.0f, __builtin_amdgcn_rcpf(1.0f + e), 1.0f);
        e = __builtin_amdgcn_exp2f(a2l * xr[j].z);
        t2 = fmaf(-2.0f, __builtin_amdgcn_rcpf(1.0f + e), 1.0f);
        e = __builtin_amdgcn_exp2f(a2l * xr[j].w);
        t3 = fmaf(-2.0f, __builtin_amdgcn_rcpf(1.0f + e), 1.0f);
        uint2 hq;
        hq.x = cvt_pk_bf16(t0, t1);
        hq.y = cvt_pk_bf16(t2, t3);
        *reinterpret_cast<uint2*>(&hA[(j * 8 + rl) * PADW + cl]) = hq;
    }

    // ---- G fragments (8 KB/wave, L2-resident) + C0 for this wave's cols ----
    short8 gf[2][4];
    float4 c0v[2];
#pragma unroll
    for (int nt = 0; nt < 2; ++nt) {
        const int c = colb + nt * 16 + lrow;
#pragma unroll
        for (int kt = 0; kt < 4; ++kt)
            gf[nt][kt] = *reinterpret_cast<const short8*>(
                &Gt[c * SIZE + kt * 32 + slot * 8]);
        c0v[nt] = *reinterpret_cast<const float4*>(&C0[colb + nt * 16 + slot * 4]);
    }

    __syncthreads();  // B1: hA published

    // half-pass: MFMA rows [r0, r0+32) -> oA, then linear epilogue of the half
    auto conv_half = [&](int mt0) __attribute__((always_inline)) {
#pragma unroll
        for (int mt = mt0; mt < mt0 + 2; ++mt) {
            short8 hf[4];
#pragma unroll
            for (int kt = 0; kt < 4; ++kt)
                hf[kt] = *reinterpret_cast<const short8*>(
                    &hA[(mt * 16 + lrow) * PADW + kt * 32 + slot * 8]);
#pragma unroll
            for (int nt = 0; nt < 2; ++nt) {
                f32x4 a = {0.f, 0.f, 0.f, 0.f};
#pragma unroll
                for (int kt = 0; kt < 4; ++kt)
                    a = __builtin_amdgcn_mfma_f32_16x16x32_bf16(gf[nt][kt], hf[kt],
                                                                a, 0, 0, 0);
                // D: row = 16mt + lrow; cols = colb + 16nt + 4*slot + reg
                uint2 o;
                o.x = cvt_pk_bf16(a[0] + c0v[nt].x, a[1] + c0v[nt].y);
                o.y = cvt_pk_bf16(a[2] + c0v[nt].z, a[3] + c0v[nt].w);
                *reinterpret_cast<uint2*>(
                    &oA[((mt - mt0) * 16 + lrow) * PADW + colb + nt * 16 +
                        slot * 4]) = o;
            }
        }
    };
    auto epi_half = [&](int j0) __attribute__((always_inline)) {
#pragma unroll
        for (int j = j0; j < j0 + 4; ++j) {
            const uint2 ov = *reinterpret_cast<const uint2*>(
                &oA[((j - j0) * 8 + rl) * PADW + cl]);
            f32x4 r;
            r[0] = __uint_as_float(ov.x << 16) + xr[j].x;
            r[1] = __uint_as_float(ov.x & 0xffff0000u) + xr[j].y;
            r[2] = __uint_as_float(ov.y << 16) + xr[j].z;
            r[3] = __uint_as_float(ov.y & 0xffff0000u) + xr[j].w;
            // NONTEMPORAL: out is never read; keep it out of L2/L3 so x stays
            // cache-resident. Wave-contiguous 1KB stores -> full lines.
            __builtin_nontemporal_store(
                r, reinterpret_cast<f32x4*>(&out[base + j * 1024 + tid * 4]));
        }
    };

    conv_half(0);          // rows 0..31 -> oA
    __syncthreads();       // B2: oA(half 0) published
    epi_half(0);           // store out rows 0..31
    __syncthreads();       // B3: all oA reads retired before overwrite
    conv_half(2);          // rows 32..63 -> oA
    __syncthreads();       // B4: oA(half 1) published
    epi_half(4);           // store out rows 32..63
}

extern "C" void kernel_launch(void* const* d_in, const int* in_sizes, int n_in,
                              void* d_out, int out_size, void* d_ws, size_t ws_size,
                              hipStream_t stream) {
    const float* x = (const float*)d_in[0];
    const float* alpha = (const float*)d_in[1];
    const float* dyt_w = (const float*)d_in[2];
    const float* dyt_b = (const float*)d_in[3];
    // d_in[4] = a_real, d_in[5] = a_imag, d_in[8] = ffn_bias: dead code in reference
    const float* b_real = (const float*)d_in[6];
    const float* b_imag = (const float*)d_in[7];
    float* out = (float*)d_out;

    unsigned short* Gt = (unsigned short*)d_ws;            // 32 KB bf16
    float* C0 = (float*)((char*)d_ws + SIZE * SIZE * 2);   // 512 B f32

    build_gt<<<1, 128, 0, stream>>>(b_real, b_imag, dyt_w, dyt_b, Gt, C0);

    const int rows = out_size / SIZE;   // 262144
    const int nblocks = rows / 64;      // 4096
    fourier_main<<<nblocks, 256, 0, stream>>>(x, alpha, Gt, C0, out);
}